// Round 2
// baseline (1953.508 us; speedup 1.0000x reference)
//
#include <hip/hip_runtime.h>
#include <hip/hip_bf16.h>
#include <math.h>

// Problem constants (fixed by setup_inputs): B=32 graphs, N=256 nodes/graph, D=128.
#define DD   128
#define NPG  256
#define NGR  32
#define TTOT 8192
#define LOG2E2 2.8853900817779268f   // 2*log2(e):  e^{2x} = 2^{x*LOG2E2}

__device__ __forceinline__ float dot4(float4 a, float4 b){
  return a.x*b.x + a.y*b.y + a.z*b.z + a.w*b.w;
}
__device__ __forceinline__ float wave_sum64(float x){
  #pragma unroll
  for (int off=32; off>0; off>>=1) x += __shfl_xor(x, off, 64);
  return x;
}

// ---------------- Kernel 1: parallel precompute ----------------
// keys = l2norm(relu(emb@Wk1.T+bk1)@Wk2.T+bk2)   [8192,128]
// gi_all = emb@W_ih.T + b_ih                      [8192,384]
// 256 blocks x 256 threads, 32 nodes per block; weights staged in LDS.

__device__ __forceinline__ void load_w128(float* Ws, const float* __restrict__ W, int t){
  const float4* src = (const float4*)W;
  #pragma unroll
  for (int m=0;m<16;m++){
    int idx = m*256+t; int r = idx>>5, c4 = idx&31;
    float4 val = src[idx];
    float* dst = &Ws[r*129 + c4*4];   // odd stride 129 -> conflict-free row reads
    dst[0]=val.x; dst[1]=val.y; dst[2]=val.z; dst[3]=val.w;
  }
}

__device__ __forceinline__ void mm_tile(const float* __restrict__ inS, const float* __restrict__ Ws,
                                        float acc[4][4], int jg, int ng){
  #pragma unroll
  for(int r=0;r<4;r++)
    #pragma unroll
    for(int c=0;c<4;c++) acc[r][c]=0.f;
  #pragma unroll 4
  for (int k=0;k<128;k++){
    float w[4], x[4];
    #pragma unroll
    for (int r=0;r<4;r++) w[r] = Ws[(jg*4+r)*129+k];
    #pragma unroll
    for (int c=0;c<4;c++) x[c] = inS[(ng*4+c)*129+k];
    #pragma unroll
    for (int r=0;r<4;r++)
      #pragma unroll
      for (int c=0;c<4;c++) acc[r][c] += w[r]*x[c];
  }
}

__global__ __launch_bounds__(256) void precompute_kernel(
    const float* __restrict__ emb,
    const float* __restrict__ Wk1, const float* __restrict__ bk1,
    const float* __restrict__ Wk2, const float* __restrict__ bk2,
    const float* __restrict__ Wih, const float* __restrict__ bih,
    float* __restrict__ keys, float* __restrict__ giall)
{
  __shared__ __align__(16) float xs[32*129];
  __shared__ __align__(16) float Ws[128*129];
  __shared__ __align__(16) float hs[32*129];
  __shared__ __align__(16) float os[32*129];
  __shared__ float nrm[32];
  const int t  = threadIdx.x;
  const int n0 = blockIdx.x * 32;
  const int ng = t & 7, jg = t >> 3;   // 8 node-groups x 32 row-groups

  { // stage 32 embedding rows
    const float4* src = (const float4*)emb + (size_t)n0*32;
    #pragma unroll
    for (int m=0;m<4;m++){
      int idx = m*256+t; int n = idx>>5, c4 = idx&31;
      float4 val = src[idx];
      float* dst = &xs[n*129 + c4*4];
      dst[0]=val.x; dst[1]=val.y; dst[2]=val.z; dst[3]=val.w;
    }
  }
  load_w128(Ws, Wk1, t);
  __syncthreads();
  { // hidden = relu(x@Wk1.T + bk1)
    float acc[4][4];
    mm_tile(xs, Ws, acc, jg, ng);
    #pragma unroll
    for (int r=0;r<4;r++){
      float bb = bk1[jg*4+r];
      #pragma unroll
      for (int c=0;c<4;c++) hs[(ng*4+c)*129 + jg*4+r] = fmaxf(acc[r][c]+bb, 0.f);
    }
  }
  __syncthreads();
  load_w128(Ws, Wk2, t);
  __syncthreads();
  { // out = hidden@Wk2.T + bk2
    float acc[4][4];
    mm_tile(hs, Ws, acc, jg, ng);
    #pragma unroll
    for (int r=0;r<4;r++){
      float bb = bk2[jg*4+r];
      #pragma unroll
      for (int c=0;c<4;c++) os[(ng*4+c)*129 + jg*4+r] = acc[r][c]+bb;
    }
  }
  __syncthreads();
  if (t<32){ // per-node l2 norm
    float ss=0.f;
    for (int j=0;j<128;j++){ float x = os[t*129+j]; ss += x*x; }
    nrm[t] = sqrtf(ss);
  }
  __syncthreads();
  #pragma unroll
  for (int m=0;m<16;m++){
    int idx = m*256+t; int n = idx>>7, j = idx&127;
    keys[(size_t)(n0+n)*128 + j] = os[n*129+j] / fmaxf(nrm[n], 1e-12f);
  }
  // gi = x@W_ih.T + b_ih, three 128-row chunks
  for (int c=0;c<3;c++){
    __syncthreads();
    load_w128(Ws, Wih + c*16384, t);
    __syncthreads();
    float acc[4][4];
    mm_tile(xs, Ws, acc, jg, ng);
    #pragma unroll
    for (int r=0;r<4;r++){
      float bb = bih[c*128 + jg*4+r];
      #pragma unroll
      for (int cc=0;cc<4;cc++)
        giall[(size_t)(n0 + ng*4+cc)*384 + c*128 + jg*4 + r] = acc[r][cc] + bb;
    }
  }
}

// ---------------- Kernel 2: sequential decode ----------------
// 32 blocks (1 per graph) x 512 threads. 255 steps in-kernel.
// W_hh (3 rows/4-lane group) + Wq1/Wq2 (1 row/group) live in registers.
// Graph's keys live in LDS (stride 132 floats = 33 float4, conflict-free).

__global__ __launch_bounds__(512,2) void decode_kernel(
    const float* __restrict__ emb,
    const float* __restrict__ keys, const float* __restrict__ giall,
    const float* __restrict__ Whh, const float* __restrict__ bhh,
    const float* __restrict__ Wq1, const float* __restrict__ bq1,
    const float* __restrict__ Wq2, const float* __restrict__ bq2,
    const float* __restrict__ v,   const float* __restrict__ Wh,
    const float* __restrict__ bh,  const int* __restrict__ start_nodes,
    float* __restrict__ tours_o, float* __restrict__ lp_o)
{
  __shared__ __align__(16) float keys_s[256*132];  // 132 KB
  __shared__ __align__(16) float h_s[128];
  __shared__ __align__(16) float q_s[128];
  __shared__ __align__(16) float qh_s[128];
  __shared__ __align__(16) float v_s[128];
  __shared__ float bq1_s[128], bq2_s[128];
  __shared__ float gis[384], ghs[384], bhh_s[384];
  __shared__ __align__(16) float spart[512];
  __shared__ float sc[256];
  __shared__ float redv[8]; __shared__ int redi[8]; __shared__ float red2[8];
  __shared__ int list_s[256], pos_s[256];
  __shared__ int cur_sh;

  const int t = threadIdx.x;
  const int b = blockIdx.x;
  const int g = t >> 2, s = t & 3;   // 128 groups of 4 lanes; each lane owns a 32-wide k-chunk

  // register-resident weights: W_hh rows 3g..3g+2, Wq1/Wq2 row g (cols s*32..s*32+31)
  float4 whh4[3][8], wq14[8], wq24[8];
  {
    const float4* w0  = (const float4*)(Whh + (size_t)(3*g+0)*128 + s*32);
    const float4* w1  = (const float4*)(Whh + (size_t)(3*g+1)*128 + s*32);
    const float4* w2  = (const float4*)(Whh + (size_t)(3*g+2)*128 + s*32);
    const float4* q1p = (const float4*)(Wq1 + (size_t)g*128 + s*32);
    const float4* q2p = (const float4*)(Wq2 + (size_t)g*128 + s*32);
    #pragma unroll
    for (int i=0;i<8;i++){
      whh4[0][i]=w0[i]; whh4[1][i]=w1[i]; whh4[2][i]=w2[i];
      wq14[i]=q1p[i];   wq24[i]=q2p[i];
    }
  }

  if (t<128){ v_s[t]=v[t]; bq1_s[t]=bq1[t]; bq2_s[t]=bq2[t]; }
  if (t<384) bhh_s[t]=bhh[t];
  if (t<256){ list_s[t]=t; pos_s[t]=t; }
  { // keys -> LDS
    const float4* src = (const float4*)(keys + (size_t)b*256*128);
    float4* dst = (float4*)keys_s;
    #pragma unroll
    for (int m=0;m<16;m++){
      int idx = m*512+t; int n = idx>>5, c4 = idx&31;
      dst[n*33+c4] = src[idx];
    }
  }
  { // graph-context partial sums (mean of node embeddings)
    int d = t & 127, part = t >> 7;
    float a = 0.f;
    const float* base = emb + (size_t)(b*256 + part*64)*128 + d;
    for (int i=0;i<64;i++) a += base[(size_t)i*128];
    spart[part*128+d] = a;
  }
  if (t==0) cur_sh = start_nodes[b];
  __syncthreads();
  if (t<128) qh_s[t] = (spart[t]+spart[128+t]+spart[256+t]+spart[384+t]) * (1.f/256.f);
  __syncthreads();
  if (t<128){ // hidden0 = gctx@Wh.T + bh
    float a = bh[t];
    const float* wr = Wh + (size_t)t*128;
    for (int k=0;k<128;k++) a += wr[k]*qh_s[k];
    h_s[t] = a;
  }
  { // sum(v) for the tanh rearrangement: v.tanh = sum(v) - 2*sum(v*sigmoid-like)
    float xv = (t<128) ? v_s[t] : 0.f;
    xv = wave_sum64(xv);
    if ((t&63)==0) red2[t>>6] = xv;
  }
  __syncthreads();
  float sv = 0.f;
  #pragma unroll
  for (int w=0;w<8;w++) sv += red2[w];

  for (int step=0; step<255; step++){
    const int V   = 255 - step;        // valid count after removing current
    const int cur = cur_sh;            // stable: written before last barrier
    const int curl = cur - b*256;

    if (t==0){
      tours_o[b*256+step] = (float)cur;
      int p = pos_s[curl]; int last = list_s[V];   // swap-remove current
      list_s[p] = last; pos_s[last] = p;
    }
    if (t<384) gis[t] = giall[(size_t)cur*384 + t];   // x@W_ih.T + b_ih gathered
    __syncthreads();                                   // B1

    { // gh = h@W_hh.T (3 rows per 4-lane group, 32-el chunks, quad shuffle-reduce)
      float a0=0.f,a1=0.f,a2=0.f;
      const float4* hc4 = (const float4*)(h_s + s*32);
      #pragma unroll
      for (int i=0;i<8;i++){
        float4 hv = hc4[i];
        a0 += dot4(whh4[0][i], hv);
        a1 += dot4(whh4[1][i], hv);
        a2 += dot4(whh4[2][i], hv);
      }
      a0 += __shfl_xor(a0,1,64); a0 += __shfl_xor(a0,2,64);
      a1 += __shfl_xor(a1,1,64); a1 += __shfl_xor(a1,2,64);
      a2 += __shfl_xor(a2,1,64); a2 += __shfl_xor(a2,2,64);
      if (s==0){
        ghs[3*g+0]=a0+bhh_s[3*g+0];
        ghs[3*g+1]=a1+bhh_s[3*g+1];
        ghs[3*g+2]=a2+bhh_s[3*g+2];
      }
    }
    __syncthreads();                                   // B2
    if (t<128){ // GRU gates (r,z,n) and h update
      float ir = gis[t]     + ghs[t];
      float iz = gis[128+t] + ghs[128+t];
      float r  = 1.f/(1.f+expf(-ir));
      float z  = 1.f/(1.f+expf(-iz));
      float n  = tanhf(gis[256+t] + r*ghs[256+t]);
      h_s[t] = (1.f-z)*n + z*h_s[t];
    }
    __syncthreads();                                   // B3
    { // qh = relu(h@Wq1.T + bq1)
      float a=0.f;
      const float4* hc4 = (const float4*)(h_s + s*32);
      #pragma unroll
      for (int i=0;i<8;i++) a += dot4(wq14[i], hc4[i]);
      a += __shfl_xor(a,1,64); a += __shfl_xor(a,2,64);
      if (s==0) qh_s[g] = fmaxf(a + bq1_s[g], 0.f);
    }
    __syncthreads();                                   // B4
    { // q_raw = qh@Wq2.T + bq2 ; fused sum-of-squares partial
      float a=0.f;
      const float4* qc4 = (const float4*)(qh_s + s*32);
      #pragma unroll
      for (int i=0;i<8;i++) a += dot4(wq24[i], qc4[i]);
      a += __shfl_xor(a,1,64); a += __shfl_xor(a,2,64);
      float qval = a + bq2_s[g];
      if (s==0) q_s[g] = qval;
      float ssv = (s==0) ? qval*qval : 0.f;
      ssv = wave_sum64(ssv);
      if ((t&63)==0) red2[t>>6] = ssv;
    }
    __syncthreads();                                   // B5
    { // l2-normalize q (all threads redundantly combine partials -> no extra barrier)
      float ss=0.f;
      #pragma unroll
      for (int w=0;w<8;w++) ss += red2[w];
      float nrm = fmaxf(sqrtf(ss), 1e-12f);
      if (t<128) q_s[t] = q_s[t] / nrm;
    }
    __syncthreads();                                   // B6
    { // scores over compacted unvisited list: s_i = sum_d v_d * tanh(k_id + q_d)
      // tanh(x) = 1 - 2/(1+e^{2x}); score = sv - 2*sum_d v_d/(1+e^{2x})
      int p = t & 255, half = t >> 8;    // 2 threads per position, 64 dims each
      if (p < V){
        int i = list_s[p];
        const float4* kr = (const float4*)(keys_s + i*132) + half*16;
        const float4* qr = (const float4*)q_s + half*16;
        const float4* vr = (const float4*)v_s + half*16;
        float4 acc = {0.f,0.f,0.f,0.f};
        #pragma unroll
        for (int j=0;j<16;j++){
          float4 kv = kr[j], qv = qr[j], vv = vr[j];
          float e, rr;
          e  = __builtin_amdgcn_exp2f((kv.x+qv.x)*LOG2E2);
          rr = __builtin_amdgcn_rcpf(1.f+e); acc.x += vv.x*rr;
          e  = __builtin_amdgcn_exp2f((kv.y+qv.y)*LOG2E2);
          rr = __builtin_amdgcn_rcpf(1.f+e); acc.y += vv.y*rr;
          e  = __builtin_amdgcn_exp2f((kv.z+qv.z)*LOG2E2);
          rr = __builtin_amdgcn_rcpf(1.f+e); acc.z += vv.z*rr;
          e  = __builtin_amdgcn_exp2f((kv.w+qv.w)*LOG2E2);
          rr = __builtin_amdgcn_rcpf(1.f+e); acc.w += vv.w*rr;
        }
        spart[half*256 + p] = acc.x+acc.y+acc.z+acc.w;
      }
    }
    __syncthreads();                                   // B7
    { // combine halves; block argmax (first-index tie-break = min original index)
      int p = t & 255;
      float val = -INFINITY; int idx = 0x7fffffff;
      if (p < V){
        val = sv - 2.f*(spart[p] + spart[256+p]);
        idx = list_s[p];
        if (t < 256) sc[p] = val;      // own slot; re-read by same thread only
      }
      #pragma unroll
      for (int off=32; off>0; off>>=1){
        float ov = __shfl_xor(val, off, 64); int oi = __shfl_xor(idx, off, 64);
        if (ov > val || (ov == val && oi < idx)){ val = ov; idx = oi; }
      }
      if ((t&63)==0){ redv[t>>6]=val; redi[t>>6]=idx; }
    }
    __syncthreads();                                   // B8
    { // final argmax (redundant per-thread) + softmax denominator partials
      float m = redv[0]; int besti = redi[0];
      #pragma unroll
      for (int w=1;w<8;w++){
        float ov=redv[w]; int oi=redi[w];
        if (ov > m || (ov==m && oi<besti)){ m=ov; besti=oi; }
      }
      float e = 0.f;
      if (t < 256 && t < V) e = expf(sc[t] - m);
      e = wave_sum64(e);
      if ((t&63)==0) red2[t>>6] = e;
      __syncthreads();                                 // B9
      if (t==0){
        float sum=0.f;
        #pragma unroll
        for (int w=0;w<8;w++) sum += red2[w];
        float lp = logf(1.f/sum + 1e-10f);   // selected prob = exp(m-m)/sum = 1/sum
        lp_o[b*255+step] = lp;
        cur_sh = b*256 + besti;
      }
    }
    __syncthreads();                                   // B10
  }
  if (t==0) tours_o[b*256+255] = (float)cur_sh;
}

extern "C" void kernel_launch(void* const* d_in, const int* in_sizes, int n_in,
                              void* d_out, int out_size, void* d_ws, size_t ws_size,
                              hipStream_t stream) {
  const float* emb  = (const float*)d_in[0];
  const int*   startn = (const int*)d_in[1];
  // d_in[2] batch_idx unused (contiguous equal-size graphs by construction)
  const float* Wq1 = (const float*)d_in[3];  const float* bq1 = (const float*)d_in[4];
  const float* Wq2 = (const float*)d_in[5];  const float* bq2 = (const float*)d_in[6];
  const float* Wk1 = (const float*)d_in[7];  const float* bk1 = (const float*)d_in[8];
  const float* Wk2 = (const float*)d_in[9];  const float* bk2 = (const float*)d_in[10];
  const float* Wih = (const float*)d_in[11]; const float* Whh = (const float*)d_in[12];
  const float* bih = (const float*)d_in[13]; const float* bhh = (const float*)d_in[14];
  const float* v   = (const float*)d_in[15]; const float* Wh  = (const float*)d_in[16];
  const float* bh  = (const float*)d_in[17];

  float* keys  = (float*)d_ws;              // 8192*128 fp32 = 4 MB
  float* giall = keys + (size_t)TTOT*DD;    // 8192*384 fp32 = 12 MB

  float* outp = (float*)d_out;   // float32 outputs: tours [32*256] then log_probs [32*255]

  precompute_kernel<<<256, 256, 0, stream>>>(emb, Wk1, bk1, Wk2, bk2, Wih, bih, keys, giall);
  decode_kernel<<<NGR, 512, 0, stream>>>(emb, keys, giall, Whh, bhh, Wq1, bq1, Wq2, bq2,
                                         v, Wh, bh, startn, outp, outp + TTOT);
}

// Round 3
// 1302.895 us; speedup vs baseline: 1.4994x; 1.4994x over previous
//
#include <hip/hip_runtime.h>
#include <hip/hip_bf16.h>
#include <math.h>

// B=32 graphs, N=256 nodes/graph, D=128.
#define DD   128
#define NPG  256
#define NGR  32
#define TTOT 8192
#define LOG2E  1.4426950408889634f
#define LOG2E2 2.8853900817779268f   // 2*log2(e)

__device__ __forceinline__ float dot4(float4 a, float4 b){
  return a.x*b.x + a.y*b.y + a.z*b.z + a.w*b.w;
}
__device__ __forceinline__ float wave_sum64(float x){
  #pragma unroll
  for (int off=32; off>0; off>>=1) x += __shfl_xor(x, off, 64);
  return x;
}
__device__ __forceinline__ float sigfast(float x){
  return __builtin_amdgcn_rcpf(1.f + __builtin_amdgcn_exp2f(-x*LOG2E));
}
__device__ __forceinline__ float tanhfast(float y){
  return 1.f - 2.f*__builtin_amdgcn_rcpf(1.f + __builtin_amdgcn_exp2f(y*LOG2E2));
}

// ---------------- Kernel 1: parallel precompute ----------------
// T = tanh(l2norm(relu(emb@Wk1.T+bk1)@Wk2.T+bk2))  [8192,128]  (tanh folded in!)
// gi_all = emb@W_ih.T + b_ih                        [8192,384]

__device__ __forceinline__ void load_w128(float* Ws, const float* __restrict__ W, int t){
  const float4* src = (const float4*)W;
  #pragma unroll
  for (int m=0;m<16;m++){
    int idx = m*256+t; int r = idx>>5, c4 = idx&31;
    float4 val = src[idx];
    float* dst = &Ws[r*129 + c4*4];
    dst[0]=val.x; dst[1]=val.y; dst[2]=val.z; dst[3]=val.w;
  }
}

__device__ __forceinline__ void mm_tile(const float* __restrict__ inS, const float* __restrict__ Ws,
                                        float acc[4][4], int jg, int ng){
  #pragma unroll
  for(int r=0;r<4;r++)
    #pragma unroll
    for(int c=0;c<4;c++) acc[r][c]=0.f;
  #pragma unroll 4
  for (int k=0;k<128;k++){
    float w[4], x[4];
    #pragma unroll
    for (int r=0;r<4;r++) w[r] = Ws[(jg*4+r)*129+k];
    #pragma unroll
    for (int c=0;c<4;c++) x[c] = inS[(ng*4+c)*129+k];
    #pragma unroll
    for (int r=0;r<4;r++)
      #pragma unroll
      for (int c=0;c<4;c++) acc[r][c] += w[r]*x[c];
  }
}

__global__ __launch_bounds__(256) void precompute_kernel(
    const float* __restrict__ emb,
    const float* __restrict__ Wk1, const float* __restrict__ bk1,
    const float* __restrict__ Wk2, const float* __restrict__ bk2,
    const float* __restrict__ Wih, const float* __restrict__ bih,
    float* __restrict__ keysT, float* __restrict__ giall)
{
  __shared__ __align__(16) float xs[32*129];
  __shared__ __align__(16) float Ws[128*129];
  __shared__ __align__(16) float hs[32*129];
  __shared__ __align__(16) float os[32*129];
  __shared__ float nrm[32];
  const int t  = threadIdx.x;
  const int n0 = blockIdx.x * 32;
  const int ng = t & 7, jg = t >> 3;

  {
    const float4* src = (const float4*)emb + (size_t)n0*32;
    #pragma unroll
    for (int m=0;m<4;m++){
      int idx = m*256+t; int n = idx>>5, c4 = idx&31;
      float4 val = src[idx];
      float* dst = &xs[n*129 + c4*4];
      dst[0]=val.x; dst[1]=val.y; dst[2]=val.z; dst[3]=val.w;
    }
  }
  load_w128(Ws, Wk1, t);
  __syncthreads();
  {
    float acc[4][4];
    mm_tile(xs, Ws, acc, jg, ng);
    #pragma unroll
    for (int r=0;r<4;r++){
      float bb = bk1[jg*4+r];
      #pragma unroll
      for (int c=0;c<4;c++) hs[(ng*4+c)*129 + jg*4+r] = fmaxf(acc[r][c]+bb, 0.f);
    }
  }
  __syncthreads();
  load_w128(Ws, Wk2, t);
  __syncthreads();
  {
    float acc[4][4];
    mm_tile(hs, Ws, acc, jg, ng);
    #pragma unroll
    for (int r=0;r<4;r++){
      float bb = bk2[jg*4+r];
      #pragma unroll
      for (int c=0;c<4;c++) os[(ng*4+c)*129 + jg*4+r] = acc[r][c]+bb;
    }
  }
  __syncthreads();
  if (t<32){
    float ss=0.f;
    for (int j=0;j<128;j++){ float x = os[t*129+j]; ss += x*x; }
    nrm[t] = sqrtf(ss);
  }
  __syncthreads();
  #pragma unroll
  for (int m=0;m<16;m++){
    int idx = m*256+t; int n = idx>>7, j = idx&127;
    keysT[(size_t)(n0+n)*128 + j] = tanhf(os[n*129+j] / fmaxf(nrm[n], 1e-12f));
  }
  for (int c=0;c<3;c++){
    __syncthreads();
    load_w128(Ws, Wih + c*16384, t);
    __syncthreads();
    float acc[4][4];
    mm_tile(xs, Ws, acc, jg, ng);
    #pragma unroll
    for (int r=0;r<4;r++){
      float bb = bih[c*128 + jg*4+r];
      #pragma unroll
      for (int cc=0;cc<4;cc++)
        giall[(size_t)(n0 + ng*4+cc)*384 + c*128 + jg*4 + r] = acc[r][cc] + bb;
    }
  }
}

// ---------------- Kernel 2: sequential decode ----------------
// 32 blocks x 512 threads; 255 steps; 6 barriers/step.
// Quad-group g owns W_hh gate rows {g,128+g,256+g} -> GRU fused after quad-reduce.
// tanh(k+q) = (T+tq)/(1+T*tq) with T precomputed, tq once/step -> 1 trans/elem.

__global__ __launch_bounds__(512,2) void decode_kernel(
    const float* __restrict__ emb,
    const float* __restrict__ keysT, const float* __restrict__ giall,
    const float* __restrict__ Whh, const float* __restrict__ bhh,
    const float* __restrict__ Wq1, const float* __restrict__ bq1,
    const float* __restrict__ Wq2, const float* __restrict__ bq2,
    const float* __restrict__ v,   const float* __restrict__ Wh,
    const float* __restrict__ bh,  const int* __restrict__ start_nodes,
    float* __restrict__ tours_o, float* __restrict__ lp_o)
{
  __shared__ __align__(16) float keys_s[256*132];  // tanh(keys), stride 132
  __shared__ __align__(16) float h_s[2][128];      // double-buffered hidden
  __shared__ __align__(16) float qh_s[128];
  __shared__ __align__(16) float q_s[128];
  __shared__ __align__(16) float tq_s[128];
  __shared__ __align__(16) float v_s[128];
  __shared__ __align__(16) float mask_s[256];      // 0 valid, -inf visited
  __shared__ __align__(16) float spart[512];       // init only
  __shared__ float redv[8]; __shared__ int redi[8]; __shared__ float red2[8];

  const int t = threadIdx.x;
  const int b = blockIdx.x;
  const int g = t >> 2, s = t & 3;
  const int l = t & 63, w = t >> 6;
  const int p    = w*32 + (l & 31);   // score position
  const int half = l >> 5;            // 0: dims 0..63, 1: dims 64..127

  // register-resident weights: W_hh rows g,128+g,256+g; Wq1/Wq2 row g (cols s*32..)
  float4 whh4[3][8], wq14[8], wq24[8];
  {
    const float4* w0  = (const float4*)(Whh + (size_t)(g      )*128 + s*32);
    const float4* w1  = (const float4*)(Whh + (size_t)(128 + g)*128 + s*32);
    const float4* w2  = (const float4*)(Whh + (size_t)(256 + g)*128 + s*32);
    const float4* q1p = (const float4*)(Wq1 + (size_t)g*128 + s*32);
    const float4* q2p = (const float4*)(Wq2 + (size_t)g*128 + s*32);
    #pragma unroll
    for (int i=0;i<8;i++){
      whh4[0][i]=w0[i]; whh4[1][i]=w1[i]; whh4[2][i]=w2[i];
      wq14[i]=q1p[i];   wq24[i]=q2p[i];
    }
  }
  const float br = bhh[g], bz = bhh[128+g], bn = bhh[256+g];
  const float b1g = bq1[g], b2g = bq2[g];

  if (t<128) v_s[t] = v[t];
  if (t<256) mask_s[t] = 0.f;
  { // tanh-keys -> LDS
    const float4* src = (const float4*)(keysT + (size_t)b*256*128);
    float4* dst = (float4*)keys_s;
    #pragma unroll
    for (int m=0;m<16;m++){
      int idx = m*512+t; int n = idx>>5, c4 = idx&31;
      dst[n*33+c4] = src[idx];
    }
  }
  { // graph-context partial sums
    int d = t & 127, part = t >> 7;
    float a = 0.f;
    const float* base = emb + (size_t)(b*256 + part*64)*128 + d;
    for (int i=0;i<64;i++) a += base[(size_t)i*128];
    spart[part*128+d] = a;
  }
  int cur = start_nodes[b];
  __syncthreads();
  if (t<128) qh_s[t] = (spart[t]+spart[128+t]+spart[256+t]+spart[384+t]) * (1.f/256.f);
  __syncthreads();
  if (t<128){ // hidden0 = gctx@Wh.T + bh
    float a = bh[t];
    const float* wr = Wh + (size_t)t*128;
    for (int k=0;k<128;k++) a += wr[k]*qh_s[k];
    h_s[0][t] = a;
  }
  __syncthreads();

  for (int step=0; step<255; step++){
    const int par = step & 1;

    // ---- phase A: gi gather + gh dots + fused GRU -> h_s[par^1] ----
    float gir=0.f, giz=0.f, gin=0.f;
    if (s==0){
      const float* gp = giall + (size_t)cur*384 + g;
      gir = gp[0]; giz = gp[128]; gin = gp[256];
    }
    if (t==0){
      tours_o[b*256+step] = (float)cur;
      mask_s[cur - b*256] = -INFINITY;
    }
    {
      float a0=0.f,a1=0.f,a2=0.f;
      const float4* hc4 = (const float4*)(h_s[par] + s*32);
      #pragma unroll
      for (int i=0;i<8;i++){
        float4 hv = hc4[i];
        a0 += dot4(whh4[0][i], hv);
        a1 += dot4(whh4[1][i], hv);
        a2 += dot4(whh4[2][i], hv);
      }
      a0 += __shfl_xor(a0,1,64); a0 += __shfl_xor(a0,2,64);
      a1 += __shfl_xor(a1,1,64); a1 += __shfl_xor(a1,2,64);
      a2 += __shfl_xor(a2,1,64); a2 += __shfl_xor(a2,2,64);
      if (s==0){
        float r = sigfast(gir + a0 + br);
        float z = sigfast(giz + a1 + bz);
        float n = tanhfast(gin + r*(a2 + bn));
        h_s[par^1][g] = (1.f-z)*n + z*h_s[par][g];
      }
    }
    __syncthreads();                                   // B1

    { // qh = relu(h@Wq1.T + bq1)
      float a=0.f;
      const float4* hc4 = (const float4*)(h_s[par^1] + s*32);
      #pragma unroll
      for (int i=0;i<8;i++) a += dot4(wq14[i], hc4[i]);
      a += __shfl_xor(a,1,64); a += __shfl_xor(a,2,64);
      if (s==0) qh_s[g] = fmaxf(a + b1g, 0.f);
    }
    __syncthreads();                                   // B2

    { // q_raw = qh@Wq2.T + bq2 ; per-wave sum-of-squares partial
      float a=0.f;
      const float4* qc4 = (const float4*)(qh_s + s*32);
      #pragma unroll
      for (int i=0;i<8;i++) a += dot4(wq24[i], qc4[i]);
      a += __shfl_xor(a,1,64); a += __shfl_xor(a,2,64);
      float qval = a + b2g;
      if (s==0) q_s[g] = qval;
      float ssp = (s==0) ? qval*qval : 0.f;
      ssp = wave_sum64(ssp);
      if (l==0) red2[w] = ssp;
    }
    __syncthreads();                                   // B3

    if (t<128){ // tq = tanh(q / ||q||)
      float ss = 0.f;
      #pragma unroll
      for (int i=0;i<8;i++) ss += red2[i];
      float nrm = fmaxf(sqrtf(ss), 1e-12f);
      tq_s[t] = tanhfast(q_s[t] / nrm);
    }
    __syncthreads();                                   // B3b

    // ---- scores: s_p = sum_d v_d*(T+tq)/(1+T*tq), + per-wave argmax ----
    float val; int idx;
    {
      const float4* kr = (const float4*)(keys_s + p*132) + half*16;
      const float4* tr = (const float4*)tq_s + half*16;
      const float4* vr = (const float4*)v_s  + half*16;
      float acc = 0.f;
      #pragma unroll
      for (int j=0;j<16;j++){
        float4 K = kr[j], Q = tr[j], V = vr[j];
        float num, den;
        num = K.x + Q.x; den = fmaf(K.x, Q.x, 1.f);
        acc = fmaf(V.x*num, __builtin_amdgcn_rcpf(den), acc);
        num = K.y + Q.y; den = fmaf(K.y, Q.y, 1.f);
        acc = fmaf(V.y*num, __builtin_amdgcn_rcpf(den), acc);
        num = K.z + Q.z; den = fmaf(K.z, Q.z, 1.f);
        acc = fmaf(V.z*num, __builtin_amdgcn_rcpf(den), acc);
        num = K.w + Q.w; den = fmaf(K.w, Q.w, 1.f);
        acc = fmaf(V.w*num, __builtin_amdgcn_rcpf(den), acc);
      }
      acc += __shfl_xor(acc, 32, 64);    // combine dim-halves (same wave)
      val = acc + mask_s[p];             // -inf if visited
      idx = p;
      float rv = val; int ri = idx;
      #pragma unroll
      for (int off=32; off>0; off>>=1){
        float ov = __shfl_xor(rv, off, 64); int oi = __shfl_xor(ri, off, 64);
        if (ov > rv || (ov == rv && oi < ri)){ rv = ov; ri = oi; }
      }
      if (l==0){ redv[w]=rv; redi[w]=ri; }
    }
    __syncthreads();                                   // B4

    // ---- softmax partials + redundant global argmax ----
    int besti;
    {
      float m = redv[0]; besti = redi[0];
      #pragma unroll
      for (int i=1;i<8;i++){
        float ov=redv[i]; int oi=redi[i];
        if (ov > m || (ov==m && oi<besti)){ m=ov; besti=oi; }
      }
      float e = (l<32) ? __builtin_amdgcn_exp2f((val - m)*LOG2E) : 0.f;
      e = wave_sum64(e);
      if (l==0) red2[w] = e;
    }
    __syncthreads();                                   // B5

    if (t==0){
      float sum=0.f;
      #pragma unroll
      for (int i=0;i<8;i++) sum += red2[i];
      lp_o[b*255+step] = logf(1.f/sum + 1e-10f);   // chosen prob = 1/sum
    }
    cur = b*256 + besti;   // every thread knows it; no barrier needed
  }
  if (t==0) tours_o[b*256+255] = (float)cur;
}

extern "C" void kernel_launch(void* const* d_in, const int* in_sizes, int n_in,
                              void* d_out, int out_size, void* d_ws, size_t ws_size,
                              hipStream_t stream) {
  const float* emb  = (const float*)d_in[0];
  const int*   startn = (const int*)d_in[1];
  const float* Wq1 = (const float*)d_in[3];  const float* bq1 = (const float*)d_in[4];
  const float* Wq2 = (const float*)d_in[5];  const float* bq2 = (const float*)d_in[6];
  const float* Wk1 = (const float*)d_in[7];  const float* bk1 = (const float*)d_in[8];
  const float* Wk2 = (const float*)d_in[9];  const float* bk2 = (const float*)d_in[10];
  const float* Wih = (const float*)d_in[11]; const float* Whh = (const float*)d_in[12];
  const float* bih = (const float*)d_in[13]; const float* bhh = (const float*)d_in[14];
  const float* v   = (const float*)d_in[15]; const float* Wh  = (const float*)d_in[16];
  const float* bh  = (const float*)d_in[17];

  float* keysT = (float*)d_ws;               // tanh(keys) [8192*128]
  float* giall = keysT + (size_t)TTOT*DD;    // [8192*384]

  float* outp = (float*)d_out;   // tours [32*256] then log_probs [32*255]

  precompute_kernel<<<256, 256, 0, stream>>>(emb, Wk1, bk1, Wk2, bk2, Wih, bih, keysT, giall);
  decode_kernel<<<NGR, 512, 0, stream>>>(emb, keysT, giall, Whh, bhh, Wq1, bq1, Wq2, bq2,
                                         v, Wh, bh, startn, outp, outp + TTOT);
}